// Round 1
// baseline (1439.834 us; speedup 1.0000x reference)
//
#include <hip/hip_runtime.h>
#include <math.h>

// Problem constants
#define BB 8
#define NN 2048
#define DD 512

#define TS 64
#define KS 16
#define TSP (TS + 4)   // padded LDS row: 68 floats = 272 B (16B-aligned, banks rotate by 4)

// C[M,N] = alpha * A[M,K] @ B[K,N]   (row-major, batched via blockIdx.z strides)
__global__ __launch_bounds__(256) void gemm_nn_kernel(
    const float* __restrict__ A, const float* __restrict__ B, float* __restrict__ C,
    int M, int N, int K, long sA, long sB, long sC, float alpha)
{
    __shared__ float As[KS][TSP];
    __shared__ float Bs[KS][TSP];
    const int bz = blockIdx.z;
    A += (long)bz * sA; B += (long)bz * sB; C += (long)bz * sC;
    const int bm = blockIdx.y * TS, bn = blockIdx.x * TS;
    const int tid = threadIdx.x;
    const int ty = tid >> 4, tx = tid & 15;
    const int ar = tid >> 2, ac = (tid & 3) << 2;      // A-tile loader: 64 rows x 16 cols
    const int br = tid >> 4, bc = (tid & 15) << 2;     // B-tile loader: 16 rows x 64 cols

    float acc[4][4] = {};
    const float* Aptr = A + (long)(bm + ar) * K + ac;
    const float* Bptr = B + (long)br * N + bn + bc;

    for (int k0 = 0; k0 < K; k0 += KS) {
        float4 av = *(const float4*)(Aptr + k0);
        float4 bv = *(const float4*)(Bptr + (long)k0 * N);
        As[ac + 0][ar] = av.x; As[ac + 1][ar] = av.y;
        As[ac + 2][ar] = av.z; As[ac + 3][ar] = av.w;
        *(float4*)&Bs[br][bc] = bv;
        __syncthreads();
        #pragma unroll
        for (int kk = 0; kk < KS; ++kk) {
            float4 a = *(const float4*)&As[kk][ty << 2];
            float4 b = *(const float4*)&Bs[kk][tx << 2];
            float av4[4] = {a.x, a.y, a.z, a.w};
            float bv4[4] = {b.x, b.y, b.z, b.w};
            #pragma unroll
            for (int i = 0; i < 4; ++i)
                #pragma unroll
                for (int j = 0; j < 4; ++j)
                    acc[i][j] = fmaf(av4[i], bv4[j], acc[i][j]);
        }
        __syncthreads();
    }

    #pragma unroll
    for (int i = 0; i < 4; ++i) {
        float4 o;
        o.x = alpha * acc[i][0]; o.y = alpha * acc[i][1];
        o.z = alpha * acc[i][2]; o.w = alpha * acc[i][3];
        *(float4*)(C + (long)(bm + (ty << 2) + i) * N + bn + (tx << 2)) = o;
    }
}

// scores[b,q,k] = (qp[b,q,:] . kp[b,k,:]) * alpha  (+ diag importance)
// NT gemm: both operands [N][K] row-major, K is the contraction dim.
__global__ __launch_bounds__(256) void scores_kernel(
    const float* __restrict__ Q, const float* __restrict__ Kp, float* __restrict__ C,
    const float* __restrict__ si, int N, int K, float alpha)
{
    __shared__ float As[KS][TSP];
    __shared__ float Bs[KS][TSP];
    const long bo = (long)blockIdx.z * N * K;
    const float* A = Q + bo;
    const float* Bm = Kp + bo;
    float* Cc = C + (long)blockIdx.z * N * N;
    const int bm = blockIdx.y * TS, bn = blockIdx.x * TS;
    const int tid = threadIdx.x;
    const int ty = tid >> 4, tx = tid & 15;
    const int ar = tid >> 2, ac = (tid & 3) << 2;

    float acc[4][4] = {};
    const float* Aptr = A + (long)(bm + ar) * K + ac;
    const float* Bptr = Bm + (long)(bn + ar) * K + ac;

    for (int k0 = 0; k0 < K; k0 += KS) {
        float4 av = *(const float4*)(Aptr + k0);
        float4 bv = *(const float4*)(Bptr + k0);
        As[ac + 0][ar] = av.x; As[ac + 1][ar] = av.y;
        As[ac + 2][ar] = av.z; As[ac + 3][ar] = av.w;
        Bs[ac + 0][ar] = bv.x; Bs[ac + 1][ar] = bv.y;
        Bs[ac + 2][ar] = bv.z; Bs[ac + 3][ar] = bv.w;
        __syncthreads();
        #pragma unroll
        for (int kk = 0; kk < KS; ++kk) {
            float4 a = *(const float4*)&As[kk][ty << 2];
            float4 b = *(const float4*)&Bs[kk][tx << 2];
            float av4[4] = {a.x, a.y, a.z, a.w};
            float bv4[4] = {b.x, b.y, b.z, b.w};
            #pragma unroll
            for (int i = 0; i < 4; ++i)
                #pragma unroll
                for (int j = 0; j < 4; ++j)
                    acc[i][j] = fmaf(av4[i], bv4[j], acc[i][j]);
        }
        __syncthreads();
    }

    #pragma unroll
    for (int i = 0; i < 4; ++i) {
        const int gq = bm + (ty << 2) + i;
        float vals[4];
        #pragma unroll
        for (int j = 0; j < 4; ++j) {
            const int gk = bn + (tx << 2) + j;
            float v = alpha * acc[i][j];
            if (gq == gk) v += fminf(expf(si[gq]), 3.0f);
            vals[j] = v;
        }
        float4 o = make_float4(vals[0], vals[1], vals[2], vals[3]);
        *(float4*)(Cc + (long)gq * N + bn + (tx << 2)) = o;
    }
}

// In-place row softmax over 2048 cols + entropy accumulation.
// One 256-thread block per row; each thread owns 8 strided elements.
__global__ __launch_bounds__(256) void softmax_entropy_kernel(
    float* __restrict__ attn, float* __restrict__ ent)
{
    __shared__ float red[4];
    const long row = blockIdx.x;
    float* p = attn + row * (long)NN;
    const int tid = threadIdx.x;

    float v[8];
    float m = -3.4e38f;
    #pragma unroll
    for (int i = 0; i < 8; ++i) { v[i] = p[tid + (i << 8)]; m = fmaxf(m, v[i]); }
    #pragma unroll
    for (int o = 32; o; o >>= 1) m = fmaxf(m, __shfl_xor(m, o, 64));
    if ((tid & 63) == 0) red[tid >> 6] = m;
    __syncthreads();
    m = fmaxf(fmaxf(red[0], red[1]), fmaxf(red[2], red[3]));

    float s = 0.f;
    #pragma unroll
    for (int i = 0; i < 8; ++i) { v[i] = expf(v[i] - m); s += v[i]; }
    #pragma unroll
    for (int o = 32; o; o >>= 1) s += __shfl_xor(s, o, 64);
    __syncthreads();
    if ((tid & 63) == 0) red[tid >> 6] = s;
    __syncthreads();
    s = red[0] + red[1] + red[2] + red[3];

    const float inv = 1.0f / s;
    float e = 0.f;
    #pragma unroll
    for (int i = 0; i < 8; ++i) {
        const float pv = v[i] * inv;
        p[tid + (i << 8)] = pv;
        e += pv * logf(pv + 1e-10f);
    }
    #pragma unroll
    for (int o = 32; o; o >>= 1) e += __shfl_xor(e, o, 64);
    __syncthreads();
    if ((tid & 63) == 0) red[tid >> 6] = e;
    __syncthreads();
    if (tid == 0) {
        const float tot = red[0] + red[1] + red[2] + red[3];
        atomicAdd(ent, tot * (-1.0f / (float)(BB * NN)));
    }
}

extern "C" void kernel_launch(void* const* d_in, const int* in_sizes, int n_in,
                              void* d_out, int out_size, void* d_ws, size_t ws_size,
                              hipStream_t stream) {
    const float* query = (const float*)d_in[0];
    const float* key   = (const float*)d_in[1];
    const float* value = (const float*)d_in[2];
    const float* Wq    = (const float*)d_in[3];
    const float* Wk    = (const float*)d_in[4];
    const float* Wv    = (const float*)d_in[5];
    const float* si    = (const float*)d_in[6];

    float* out  = (float*)d_out;                       // [B,N,D]
    float* attn = out + (size_t)BB * NN * DD;          // [B,N,N]
    float* ent  = attn + (size_t)BB * NN * NN;         // scalar

    const size_t bnd = (size_t)BB * NN * DD;
    float* qp = (float*)d_ws;
    float* kp = qp + bnd;
    float* vp = kp + bnd;

    const dim3 blk(256);
    const float inv_sqrt_d = 0.044194173824159216f;    // 1/sqrt(512)

    // Projections: [B*N, 512] @ [512, 512]
    gemm_nn_kernel<<<dim3(DD / TS, (BB * NN) / TS, 1), blk, 0, stream>>>(
        query, Wq, qp, BB * NN, DD, DD, 0, 0, 0, 1.0f);
    gemm_nn_kernel<<<dim3(DD / TS, (BB * NN) / TS, 1), blk, 0, stream>>>(
        key, Wk, kp, BB * NN, DD, DD, 0, 0, 0, 1.0f);
    gemm_nn_kernel<<<dim3(DD / TS, (BB * NN) / TS, 1), blk, 0, stream>>>(
        value, Wv, vp, BB * NN, DD, DD, 0, 0, 0, 1.0f);

    // scores = q @ k^T / sqrt(d) + diag(min(exp(si),3)), written into attn region
    scores_kernel<<<dim3(NN / TS, NN / TS, BB), blk, 0, stream>>>(
        qp, kp, attn, si, NN, DD, inv_sqrt_d);

    // softmax in-place + entropy
    hipMemsetAsync(ent, 0, sizeof(float), stream);
    softmax_entropy_kernel<<<dim3(BB * NN), blk, 0, stream>>>(attn, ent);

    // out = attn @ v   (per batch: [2048,2048] @ [2048,512])
    gemm_nn_kernel<<<dim3(DD / TS, NN / TS, BB), blk, 0, stream>>>(
        attn, vp, out, NN, DD, NN,
        (long)NN * NN, (long)NN * DD, (long)NN * DD, 1.0f);
}

// Round 2
// 500.957 us; speedup vs baseline: 2.8742x; 2.8742x over previous
//
#include <hip/hip_runtime.h>
#include <math.h>

#define BB 8
#define NN 2048
#define DD 512

typedef _Float16 half8 __attribute__((ext_vector_type(8)));
typedef _Float16 half4 __attribute__((ext_vector_type(4)));
typedef float f32x4 __attribute__((ext_vector_type(4)));

#define GLOAD16(gp, sp) __builtin_amdgcn_global_load_lds( \
    (const __attribute__((address_space(1))) void*)(gp), \
    (__attribute__((address_space(3))) void*)(sp), 16, 0, 0)

// ---------------------------------------------------------------------------
// W transpose + fp16 split:  WT[e][d] = W[d][e]  ->  (hi, lo) fp16 pairs
// z = 0: Wq (hi+lo), z = 1: Wk (hi+lo), z = 2: Wv (hi only)
// ---------------------------------------------------------------------------
__global__ __launch_bounds__(256) void wsplit_kernel(
    const float* __restrict__ Wq, const float* __restrict__ Wk, const float* __restrict__ Wv,
    _Float16* __restrict__ qhT, _Float16* __restrict__ qlT,
    _Float16* __restrict__ khT, _Float16* __restrict__ klT,
    _Float16* __restrict__ vhT)
{
    __shared__ float t[64][65];
    const int z = blockIdx.z;
    const float* W = (z == 0) ? Wq : ((z == 1) ? Wk : Wv);
    _Float16* Ph = (z == 0) ? qhT : ((z == 1) ? khT : vhT);
    _Float16* Pl = (z == 0) ? qlT : ((z == 1) ? klT : nullptr);
    const int bx = blockIdx.x * 64, by = blockIdx.y * 64;
    const int tid = threadIdx.x;
    #pragma unroll
    for (int i = 0; i < 16; ++i) {
        const int idx = i * 256 + tid;
        const int r = idx >> 6, c = idx & 63;
        t[r][c] = W[(long)(by + r) * 512 + bx + c];
    }
    __syncthreads();
    #pragma unroll
    for (int i = 0; i < 16; ++i) {
        const int idx = i * 256 + tid;
        const int r = idx >> 6, c = idx & 63;
        const float v = t[c][r];                       // = W[by+c][bx+r]
        const _Float16 h = (_Float16)v;
        const long o = (long)(bx + r) * 512 + by + c;  // WT[e=bx+r][d=by+c]
        Ph[o] = h;
        if (z < 2) Pl[o] = (_Float16)(v - (float)h);
    }
}

// ---------------------------------------------------------------------------
// Unified NT GEMM on MFMA f32_16x16x32_f16, 128x128 tile, BK=32, 4 waves.
// D[m][n] = sum_k A[m][k] * B[n][k]   (both operands row-major over k)
// EPI 0: q/k projection  — A fp32 (reg-split), B pre-split fp16, 3 products,
//                          out = (hi,lo) fp16 row-major [M][N]
// EPI 1: v projection    — A fp32 (cvt hi),   B fp16 hi,       1 product,
//                          out = vT fp16  [b][N=512][2048]
// EPI 2: scores          — A,B pre-split fp16 (gload_lds),     3 products,
//                          out = fp32 scores*scale + diag bias
// EPI 3: attn @ v        — A,B fp16 hi (gload_lds),            1 product,
//                          out = fp32
// ---------------------------------------------------------------------------
template<int EPI>
__global__ __launch_bounds__(256) void mm_nt(
    const float* __restrict__ Af,
    const _Float16* __restrict__ Agh, const _Float16* __restrict__ Agl,
    const _Float16* __restrict__ Bgh, const _Float16* __restrict__ Bgl,
    float* __restrict__ Of, _Float16* __restrict__ Oh, _Float16* __restrict__ Ol,
    const float* __restrict__ si,
    int N, int K, long sAb, long sBb, long sOb, float scale)
{
    constexpr bool NP3    = (EPI == 0 || EPI == 2);   // 3-product split math
    constexpr bool A_FP32 = (EPI == 0 || EPI == 1);   // A staged from fp32
    constexpr bool A_SPLIT = (EPI == 0);              // A lo part needed

    __shared__ __align__(16) _Float16 smem[(NP3 ? 4 : 2) * 128 * 32];
    _Float16* Ah = smem;
    _Float16* Bh = smem + 4096;
    _Float16* Al = smem + 8192;    // used only when NP3
    _Float16* Bl = smem + 12288;   // used only when NP3

    const int tid  = threadIdx.x;
    const int lane = tid & 63;
    const int w    = tid >> 6;
    const int wr   = w >> 1, wc = w & 1;
    const int z    = blockIdx.z;
    const int bm   = blockIdx.y * 128, bn = blockIdx.x * 128;

    const float* Afz = nullptr;
    const _Float16 *Aghz = nullptr, *Aglz = nullptr;
    if constexpr (A_FP32) { Afz = Af + (long)z * sAb; }
    else { Aghz = Agh + (long)z * sAb; if constexpr (NP3) Aglz = Agl + (long)z * sAb; }
    const _Float16* Bghz = Bgh + (long)z * sBb;
    const _Float16* Bglz = nullptr;
    if constexpr (NP3) Bglz = Bgl + (long)z * sBb;

    f32x4 acc[4][4];
    #pragma unroll
    for (int i = 0; i < 4; ++i)
        #pragma unroll
        for (int j = 0; j < 4; ++j) acc[i][j] = (f32x4)0.0f;

    for (int k0 = 0; k0 < K; k0 += 32) {
        // ---- stage B tile [128 n-rows][32 k] fp16 via global_load_lds ----
        #pragma unroll
        for (int i = 0; i < 2; ++i) {
            const int c   = i * 256 + w * 64 + lane;   // 16B chunk id
            const int row = c >> 2, sl = c & 3;
            const long g  = (long)(bn + row) * K + k0 + sl * 8;
            const int lb  = (i * 256 + w * 64) * 8;    // wave-uniform LDS base
            GLOAD16(Bghz + g, Bh + lb);
            if constexpr (NP3) GLOAD16(Bglz + g, Bl + lb);
        }
        // ---- stage A tile ----
        if constexpr (A_FP32) {
            #pragma unroll
            for (int i = 0; i < 4; ++i) {
                const int c = tid + i * 256;           // float4 chunk id (1024)
                const int row = c >> 3, q4 = c & 7;
                const float4 v = *(const float4*)(Afz + (long)(bm + row) * K + k0 + q4 * 4);
                half4 h;
                h[0] = (_Float16)v.x; h[1] = (_Float16)v.y;
                h[2] = (_Float16)v.z; h[3] = (_Float16)v.w;
                *(half4*)&Ah[row * 32 + q4 * 4] = h;
                if constexpr (A_SPLIT) {
                    half4 l;
                    l[0] = (_Float16)(v.x - (float)h[0]);
                    l[1] = (_Float16)(v.y - (float)h[1]);
                    l[2] = (_Float16)(v.z - (float)h[2]);
                    l[3] = (_Float16)(v.w - (float)h[3]);
                    *(half4*)&Al[row * 32 + q4 * 4] = l;
                }
            }
        } else {
            #pragma unroll
            for (int i = 0; i < 2; ++i) {
                const int c   = i * 256 + w * 64 + lane;
                const int row = c >> 2, sl = c & 3;
                const long g  = (long)(bm + row) * K + k0 + sl * 8;
                const int lb  = (i * 256 + w * 64) * 8;
                GLOAD16(Aghz + g, Ah + lb);
                if constexpr (NP3) GLOAD16(Aglz + g, Al + lb);
            }
        }
        __syncthreads();

        // ---- fragments + MFMA ----
        half8 ah[4], bh[4], al[4], bl[4];
        #pragma unroll
        for (int f = 0; f < 4; ++f) {
            const int ar = wr * 64 + f * 16 + (lane & 15);
            const int ao = ar * 32 + ((lane >> 4) << 3);
            ah[f] = *(const half8*)&Ah[ao];
            if constexpr (NP3) al[f] = *(const half8*)&Al[ao];
            const int br = wc * 64 + f * 16 + (lane & 15);
            const int bo = br * 32 + ((lane >> 4) << 3);
            bh[f] = *(const half8*)&Bh[bo];
            if constexpr (NP3) bl[f] = *(const half8*)&Bl[bo];
        }
        #pragma unroll
        for (int i = 0; i < 4; ++i)
            #pragma unroll
            for (int j = 0; j < 4; ++j) {
                acc[i][j] = __builtin_amdgcn_mfma_f32_16x16x32_f16(ah[i], bh[j], acc[i][j], 0, 0, 0);
                if constexpr (NP3) {
                    acc[i][j] = __builtin_amdgcn_mfma_f32_16x16x32_f16(ah[i], bl[j], acc[i][j], 0, 0, 0);
                    acc[i][j] = __builtin_amdgcn_mfma_f32_16x16x32_f16(al[i], bh[j], acc[i][j], 0, 0, 0);
                }
            }
        __syncthreads();
    }

    // ---- epilogue ----
    #pragma unroll
    for (int i = 0; i < 4; ++i) {
        const int rb = bm + wr * 64 + i * 16 + ((lane >> 4) << 2);
        #pragma unroll
        for (int j = 0; j < 4; ++j) {
            const int gc = bn + wc * 64 + j * 16 + (lane & 15);
            if constexpr (EPI == 0) {
                #pragma unroll
                for (int r = 0; r < 4; ++r) {
                    const float vv = acc[i][j][r];
                    const _Float16 h = (_Float16)vv;
                    const long o = (long)(rb + r) * N + gc;
                    Oh[o] = h;
                    Ol[o] = (_Float16)(vv - (float)h);
                }
            } else if constexpr (EPI == 1) {
                half4 hv;
                #pragma unroll
                for (int r = 0; r < 4; ++r) hv[r] = (_Float16)acc[i][j][r];
                const int b = rb >> 11, rIn = rb & 2047;
                *(half4*)&Oh[((long)b * 512 + gc) * 2048 + rIn] = hv;
            } else if constexpr (EPI == 2) {
                float* O = Of + (long)z * sOb;
                #pragma unroll
                for (int r = 0; r < 4; ++r) {
                    const int gr = rb + r;
                    float vv = acc[i][j][r] * scale;
                    if (gr == gc) vv += fminf(expf(si[gr]), 3.0f);
                    O[(long)gr * N + gc] = vv;
                }
            } else {
                float* O = Of + (long)z * sOb;
                #pragma unroll
                for (int r = 0; r < 4; ++r)
                    O[(long)(rb + r) * N + gc] = acc[i][j][r];
            }
        }
    }
}

// ---------------------------------------------------------------------------
// In-place row softmax + entropy + fp16 copy of attn for the AV GEMM.
// ---------------------------------------------------------------------------
__global__ __launch_bounds__(256) void softmax_entropy_kernel(
    float* __restrict__ attn, _Float16* __restrict__ ah, float* __restrict__ ent)
{
    __shared__ float red[4];
    const long row = blockIdx.x;
    float* p = attn + row * (long)NN;
    _Float16* ph = ah + row * (long)NN;
    const int tid = threadIdx.x;

    float v[8];
    float m = -3.4e38f;
    #pragma unroll
    for (int i = 0; i < 8; ++i) { v[i] = p[tid + (i << 8)]; m = fmaxf(m, v[i]); }
    #pragma unroll
    for (int o = 32; o; o >>= 1) m = fmaxf(m, __shfl_xor(m, o, 64));
    if ((tid & 63) == 0) red[tid >> 6] = m;
    __syncthreads();
    m = fmaxf(fmaxf(red[0], red[1]), fmaxf(red[2], red[3]));

    float s = 0.f;
    #pragma unroll
    for (int i = 0; i < 8; ++i) { v[i] = expf(v[i] - m); s += v[i]; }
    #pragma unroll
    for (int o = 32; o; o >>= 1) s += __shfl_xor(s, o, 64);
    __syncthreads();
    if ((tid & 63) == 0) red[tid >> 6] = s;
    __syncthreads();
    s = red[0] + red[1] + red[2] + red[3];

    const float inv = 1.0f / s;
    float e = 0.f;
    #pragma unroll
    for (int i = 0; i < 8; ++i) {
        const float pv = v[i] * inv;
        p[tid + (i << 8)] = pv;
        ph[tid + (i << 8)] = (_Float16)pv;
        e += pv * logf(pv + 1e-10f);
    }
    #pragma unroll
    for (int o = 32; o; o >>= 1) e += __shfl_xor(e, o, 64);
    __syncthreads();
    if ((tid & 63) == 0) red[tid >> 6] = e;
    __syncthreads();
    if (tid == 0) {
        const float tot = red[0] + red[1] + red[2] + red[3];
        atomicAdd(ent, tot * (-1.0f / (float)(BB * NN)));
    }
}

extern "C" void kernel_launch(void* const* d_in, const int* in_sizes, int n_in,
                              void* d_out, int out_size, void* d_ws, size_t ws_size,
                              hipStream_t stream) {
    const float* query = (const float*)d_in[0];
    const float* key   = (const float*)d_in[1];
    const float* value = (const float*)d_in[2];
    const float* Wq    = (const float*)d_in[3];
    const float* Wk    = (const float*)d_in[4];
    const float* Wv    = (const float*)d_in[5];
    const float* si    = (const float*)d_in[6];

    float* out  = (float*)d_out;                        // [B,N,D]
    float* attn = out + (size_t)BB * NN * DD;           // [B,N,N]
    float* ent  = attn + (size_t)BB * NN * NN;          // scalar

    const size_t NK = (size_t)BB * NN * DD;             // 8.39M elements
    _Float16* ws16 = (_Float16*)d_ws;
    _Float16* qh = ws16;            // 16.8 MB each
    _Float16* ql = qh + NK;
    _Float16* kh = ql + NK;
    _Float16* kl = kh + NK;
    _Float16* vT = kl + NK;         // vT fp16 [b][512][2048]
    _Float16* WqhT = vT + NK;       // 0.5 MB each
    _Float16* WqlT = WqhT + DD * DD;
    _Float16* WkhT = WqlT + DD * DD;
    _Float16* WklT = WkhT + DD * DD;
    _Float16* WvhT = WklT + DD * DD;
    _Float16* attn_h = ws16;        // 67 MB, aliases qh..kl (dead after scores)

    const dim3 blk(256);
    const float inv_sqrt_d = 0.044194173824159216f;     // 1/sqrt(512)

    wsplit_kernel<<<dim3(8, 8, 3), blk, 0, stream>>>(Wq, Wk, Wv,
        WqhT, WqlT, WkhT, WklT, WvhT);

    // q/k projections: [16384,512] x [512,512]^T(pre-transposed), 3-product
    mm_nt<0><<<dim3(4, 128, 1), blk, 0, stream>>>(
        query, nullptr, nullptr, WqhT, WqlT, nullptr, qh, ql, nullptr,
        DD, DD, 0, 0, 0, 1.0f);
    mm_nt<0><<<dim3(4, 128, 1), blk, 0, stream>>>(
        key, nullptr, nullptr, WkhT, WklT, nullptr, kh, kl, nullptr,
        DD, DD, 0, 0, 0, 1.0f);
    // v projection, 1-product, writes vT fp16
    mm_nt<1><<<dim3(4, 128, 1), blk, 0, stream>>>(
        value, nullptr, nullptr, WvhT, nullptr, nullptr, vT, nullptr, nullptr,
        DD, DD, 0, 0, 0, 1.0f);

    // scores = q k^T / sqrt(d) + diag(min(exp(si),3)), 3-product
    mm_nt<2><<<dim3(16, 16, BB), blk, 0, stream>>>(
        nullptr, qh, ql, kh, kl, attn, nullptr, nullptr, si,
        NN, DD, (long)NN * DD, (long)NN * DD, (long)NN * NN, inv_sqrt_d);

    hipMemsetAsync(ent, 0, sizeof(float), stream);
    softmax_entropy_kernel<<<dim3(BB * NN), blk, 0, stream>>>(attn, attn_h, ent);

    // out = attn @ v : A = attn fp16 [2048][2048], B = vT fp16 [512][2048]
    mm_nt<3><<<dim3(4, 16, BB), blk, 0, stream>>>(
        nullptr, attn_h, nullptr, vT, nullptr, out, nullptr, nullptr, nullptr,
        DD, NN, (long)NN * NN, (long)DD * NN, (long)NN * DD, 1.0f);
}

// Round 3
// 348.542 us; speedup vs baseline: 4.1310x; 1.4373x over previous
//
#include <hip/hip_runtime.h>
#include <math.h>

#define BB 8
#define NN 2048
#define DD 512

typedef _Float16 half8 __attribute__((ext_vector_type(8)));
typedef _Float16 half4 __attribute__((ext_vector_type(4)));
typedef float f32x4 __attribute__((ext_vector_type(4)));

#define GLOAD16(gp, sp) __builtin_amdgcn_global_load_lds( \
    (const __attribute__((address_space(1))) void*)(gp), \
    (__attribute__((address_space(3))) void*)(sp), 16, 0, 0)

// ---------------------------------------------------------------------------
// W transpose + fp16 split:  WT[e][d] = W[d][e]  ->  (hi, lo) fp16 pairs
// z = 0: Wq (hi+lo), z = 1: Wk (hi+lo), z = 2: Wv (hi only)
// ---------------------------------------------------------------------------
__global__ __launch_bounds__(256) void wsplit_kernel(
    const float* __restrict__ Wq, const float* __restrict__ Wk, const float* __restrict__ Wv,
    _Float16* __restrict__ qhT, _Float16* __restrict__ qlT,
    _Float16* __restrict__ khT, _Float16* __restrict__ klT,
    _Float16* __restrict__ vhT)
{
    __shared__ float t[64][65];
    const int z = blockIdx.z;
    const float* W = (z == 0) ? Wq : ((z == 1) ? Wk : Wv);
    _Float16* Ph = (z == 0) ? qhT : ((z == 1) ? khT : vhT);
    _Float16* Pl = (z == 0) ? qlT : ((z == 1) ? klT : nullptr);
    const int bx = blockIdx.x * 64, by = blockIdx.y * 64;
    const int tid = threadIdx.x;
    #pragma unroll
    for (int i = 0; i < 16; ++i) {
        const int idx = i * 256 + tid;
        const int r = idx >> 6, c = idx & 63;
        t[r][c] = W[(long)(by + r) * 512 + bx + c];
    }
    __syncthreads();
    #pragma unroll
    for (int i = 0; i < 16; ++i) {
        const int idx = i * 256 + tid;
        const int r = idx >> 6, c = idx & 63;
        const float v = t[c][r];                       // = W[by+c][bx+r]
        const _Float16 h = (_Float16)v;
        const long o = (long)(bx + r) * 512 + by + c;  // WT[e=bx+r][d=by+c]
        Ph[o] = h;
        if (z < 2) Pl[o] = (_Float16)(v - (float)h);
    }
}

// ---------------------------------------------------------------------------
// Unified NT GEMM on MFMA f32_16x16x32_f16, 128x128 tile, BK=32, 4 waves.
// ---------------------------------------------------------------------------
template<int EPI>
__global__ __launch_bounds__(256) void mm_nt(
    const float* __restrict__ Af,
    const _Float16* __restrict__ Agh, const _Float16* __restrict__ Agl,
    const _Float16* __restrict__ Bgh, const _Float16* __restrict__ Bgl,
    float* __restrict__ Of, _Float16* __restrict__ Oh, _Float16* __restrict__ Ol,
    const float* __restrict__ si,
    int N, int K, long sAb, long sBb, long sOb, float scale)
{
    constexpr bool NP3    = (EPI == 0 || EPI == 2);   // 3-product split math
    constexpr bool A_FP32 = (EPI == 0 || EPI == 1);   // A staged from fp32
    constexpr bool A_SPLIT = (EPI == 0);              // A lo part needed

    __shared__ __align__(16) _Float16 smem[(NP3 ? 4 : 2) * 128 * 32];
    _Float16* Ah = smem;
    _Float16* Bh = smem + 4096;
    _Float16* Al = smem + 8192;    // used only when NP3
    _Float16* Bl = smem + 12288;   // used only when NP3

    const int tid  = threadIdx.x;
    const int lane = tid & 63;
    const int w    = tid >> 6;
    const int wr   = w >> 1, wc = w & 1;
    const int z    = blockIdx.z;
    const int bm   = blockIdx.y * 128, bn = blockIdx.x * 128;

    const float* Afz = nullptr;
    const _Float16 *Aghz = nullptr, *Aglz = nullptr;
    if constexpr (A_FP32) { Afz = Af + (long)z * sAb; }
    else { Aghz = Agh + (long)z * sAb; if constexpr (NP3) Aglz = Agl + (long)z * sAb; }
    const _Float16* Bghz = Bgh + (long)z * sBb;
    const _Float16* Bglz = nullptr;
    if constexpr (NP3) Bglz = Bgl + (long)z * sBb;

    f32x4 acc[4][4];
    #pragma unroll
    for (int i = 0; i < 4; ++i)
        #pragma unroll
        for (int j = 0; j < 4; ++j) acc[i][j] = (f32x4)0.0f;

    for (int k0 = 0; k0 < K; k0 += 32) {
        // ---- stage B tile [128 n-rows][32 k] fp16 via global_load_lds ----
        #pragma unroll
        for (int i = 0; i < 2; ++i) {
            const int c   = i * 256 + w * 64 + lane;   // 16B chunk id
            const int row = c >> 2, sl = c & 3;
            const long g  = (long)(bn + row) * K + k0 + sl * 8;
            const int lb  = (i * 256 + w * 64) * 8;    // wave-uniform LDS base
            GLOAD16(Bghz + g, Bh + lb);
            if constexpr (NP3) GLOAD16(Bglz + g, Bl + lb);
        }
        // ---- stage A tile ----
        if constexpr (A_FP32) {
            #pragma unroll
            for (int i = 0; i < 4; ++i) {
                const int c = tid + i * 256;           // float4 chunk id (1024)
                const int row = c >> 3, q4 = c & 7;
                const float4 v = *(const float4*)(Afz + (long)(bm + row) * K + k0 + q4 * 4);
                half4 h;
                h[0] = (_Float16)v.x; h[1] = (_Float16)v.y;
                h[2] = (_Float16)v.z; h[3] = (_Float16)v.w;
                *(half4*)&Ah[row * 32 + q4 * 4] = h;
                if constexpr (A_SPLIT) {
                    half4 l;
                    l[0] = (_Float16)(v.x - (float)h[0]);
                    l[1] = (_Float16)(v.y - (float)h[1]);
                    l[2] = (_Float16)(v.z - (float)h[2]);
                    l[3] = (_Float16)(v.w - (float)h[3]);
                    *(half4*)&Al[row * 32 + q4 * 4] = l;
                }
            }
        } else {
            #pragma unroll
            for (int i = 0; i < 2; ++i) {
                const int c   = i * 256 + w * 64 + lane;
                const int row = c >> 2, sl = c & 3;
                const long g  = (long)(bm + row) * K + k0 + sl * 8;
                const int lb  = (i * 256 + w * 64) * 8;
                GLOAD16(Aghz + g, Ah + lb);
                if constexpr (NP3) GLOAD16(Aglz + g, Al + lb);
            }
        }
        __syncthreads();

        // ---- fragments + MFMA ----
        half8 ah[4], bh[4], al[4], bl[4];
        #pragma unroll
        for (int f = 0; f < 4; ++f) {
            const int ar = wr * 64 + f * 16 + (lane & 15);
            const int ao = ar * 32 + ((lane >> 4) << 3);
            ah[f] = *(const half8*)&Ah[ao];
            if constexpr (NP3) al[f] = *(const half8*)&Al[ao];
            const int br = wc * 64 + f * 16 + (lane & 15);
            const int bo = br * 32 + ((lane >> 4) << 3);
            bh[f] = *(const half8*)&Bh[bo];
            if constexpr (NP3) bl[f] = *(const half8*)&Bl[bo];
        }
        #pragma unroll
        for (int i = 0; i < 4; ++i)
            #pragma unroll
            for (int j = 0; j < 4; ++j) {
                acc[i][j] = __builtin_amdgcn_mfma_f32_16x16x32_f16(ah[i], bh[j], acc[i][j], 0, 0, 0);
                if constexpr (NP3) {
                    acc[i][j] = __builtin_amdgcn_mfma_f32_16x16x32_f16(ah[i], bl[j], acc[i][j], 0, 0, 0);
                    acc[i][j] = __builtin_amdgcn_mfma_f32_16x16x32_f16(al[i], bh[j], acc[i][j], 0, 0, 0);
                }
            }
        __syncthreads();
    }

    // ---- epilogue ----
    #pragma unroll
    for (int i = 0; i < 4; ++i) {
        const int rb = bm + wr * 64 + i * 16 + ((lane >> 4) << 2);
        #pragma unroll
        for (int j = 0; j < 4; ++j) {
            const int gc = bn + wc * 64 + j * 16 + (lane & 15);
            if constexpr (EPI == 0) {
                #pragma unroll
                for (int r = 0; r < 4; ++r) {
                    const float vv = acc[i][j][r];
                    const _Float16 h = (_Float16)vv;
                    const long o = (long)(rb + r) * N + gc;
                    Oh[o] = h;
                    Ol[o] = (_Float16)(vv - (float)h);
                }
            } else if constexpr (EPI == 1) {
                half4 hv;
                #pragma unroll
                for (int r = 0; r < 4; ++r) hv[r] = (_Float16)acc[i][j][r];
                const int b = rb >> 11, rIn = rb & 2047;
                *(half4*)&Oh[((long)b * 512 + gc) * 2048 + rIn] = hv;
            } else if constexpr (EPI == 2) {
                float* O = Of + (long)z * sOb;
                #pragma unroll
                for (int r = 0; r < 4; ++r) {
                    const int gr = rb + r;
                    float vv = acc[i][j][r] * scale;
                    if (gr == gc) vv += fminf(expf(si[gr]), 3.0f);
                    O[(long)gr * N + gc] = vv;
                }
            } else {
                float* O = Of + (long)z * sOb;
                #pragma unroll
                for (int r = 0; r < 4; ++r)
                    O[(long)(rb + r) * N + gc] = acc[i][j][r];
            }
        }
    }
}

// ---------------------------------------------------------------------------
// In-place row softmax + entropy partial + fp16 copy of attn.
// One block per row; thread owns 8 CONTIGUOUS elements (float4 x2 / half8).
// Entropy via log-identity: log(p) = (s - m) - log(sum); partial -> ws array.
// ---------------------------------------------------------------------------
__global__ __launch_bounds__(256) void softmax_entropy_kernel(
    float* __restrict__ attn, _Float16* __restrict__ ah, float* __restrict__ partials)
{
    __shared__ float red[4];
    const long row = blockIdx.x;
    float* p = attn + row * (long)NN;
    _Float16* ph = ah + row * (long)NN;
    const int tid = threadIdx.x;
    const int base = tid * 8;

    float4 va = *(const float4*)(p + base);
    float4 vb = *(const float4*)(p + base + 4);
    float v[8] = {va.x, va.y, va.z, va.w, vb.x, vb.y, vb.z, vb.w};

    float m = v[0];
    #pragma unroll
    for (int i = 1; i < 8; ++i) m = fmaxf(m, v[i]);
    #pragma unroll
    for (int o = 32; o; o >>= 1) m = fmaxf(m, __shfl_xor(m, o, 64));
    if ((tid & 63) == 0) red[tid >> 6] = m;
    __syncthreads();
    m = fmaxf(fmaxf(red[0], red[1]), fmaxf(red[2], red[3]));

    float t[8];
    float s = 0.f;
    #pragma unroll
    for (int i = 0; i < 8; ++i) { t[i] = v[i] - m; v[i] = expf(t[i]); s += v[i]; }
    #pragma unroll
    for (int o = 32; o; o >>= 1) s += __shfl_xor(s, o, 64);
    __syncthreads();
    if ((tid & 63) == 0) red[tid >> 6] = s;
    __syncthreads();
    s = red[0] + red[1] + red[2] + red[3];

    const float inv = 1.0f / s;
    const float lns = logf(s);
    float e = 0.f;
    float pv[8];
    #pragma unroll
    for (int i = 0; i < 8; ++i) {
        pv[i] = v[i] * inv;
        e = fmaf(pv[i], t[i] - lns, e);
    }
    *(float4*)(p + base)     = make_float4(pv[0], pv[1], pv[2], pv[3]);
    *(float4*)(p + base + 4) = make_float4(pv[4], pv[5], pv[6], pv[7]);
    half8 h;
    #pragma unroll
    for (int i = 0; i < 8; ++i) h[i] = (_Float16)pv[i];
    *(half8*)(ph + base) = h;

    #pragma unroll
    for (int o = 32; o; o >>= 1) e += __shfl_xor(e, o, 64);
    __syncthreads();
    if ((tid & 63) == 0) red[tid >> 6] = e;
    __syncthreads();
    if (tid == 0) partials[row] = red[0] + red[1] + red[2] + red[3];
}

// Final entropy reduction: one block sums 16384 partials, writes scalar.
__global__ __launch_bounds__(256) void ent_reduce_kernel(
    const float* __restrict__ partials, float* __restrict__ ent)
{
    __shared__ float red[4];
    float s = 0.f;
    for (int i = threadIdx.x; i < BB * NN; i += 256) s += partials[i];
    #pragma unroll
    for (int o = 32; o; o >>= 1) s += __shfl_xor(s, o, 64);
    if ((threadIdx.x & 63) == 0) red[threadIdx.x >> 6] = s;
    __syncthreads();
    if (threadIdx.x == 0)
        *ent = -(red[0] + red[1] + red[2] + red[3]) / (float)(BB * NN);
}

extern "C" void kernel_launch(void* const* d_in, const int* in_sizes, int n_in,
                              void* d_out, int out_size, void* d_ws, size_t ws_size,
                              hipStream_t stream) {
    const float* query = (const float*)d_in[0];
    const float* key   = (const float*)d_in[1];
    const float* value = (const float*)d_in[2];
    const float* Wq    = (const float*)d_in[3];
    const float* Wk    = (const float*)d_in[4];
    const float* Wv    = (const float*)d_in[5];
    const float* si    = (const float*)d_in[6];

    float* out  = (float*)d_out;                        // [B,N,D]
    float* attn = out + (size_t)BB * NN * DD;           // [B,N,N]
    float* ent  = attn + (size_t)BB * NN * NN;          // scalar

    const size_t NK = (size_t)BB * NN * DD;             // 8.39M elements
    _Float16* ws16 = (_Float16*)d_ws;
    _Float16* qh = ws16;            // 16.8 MB each
    _Float16* ql = qh + NK;
    _Float16* kh = ql + NK;
    _Float16* kl = kh + NK;
    _Float16* vT = kl + NK;         // vT fp16 [b][512][2048]
    _Float16* WqhT = vT + NK;       // 0.5 MB each
    _Float16* WqlT = WqhT + DD * DD;
    _Float16* WkhT = WqlT + DD * DD;
    _Float16* WklT = WkhT + DD * DD;
    _Float16* WvhT = WklT + DD * DD;
    float* partials = (float*)(WvhT + DD * DD);         // 64 KB
    _Float16* attn_h = ws16;        // 67 MB, aliases qh..kl (dead after scores)

    const dim3 blk(256);
    const float inv_sqrt_d = 0.044194173824159216f;     // 1/sqrt(512)

    wsplit_kernel<<<dim3(8, 8, 3), blk, 0, stream>>>(Wq, Wk, Wv,
        WqhT, WqlT, WkhT, WklT, WvhT);

    // q/k projections: [16384,512] x [512,512]^T(pre-transposed), 3-product
    mm_nt<0><<<dim3(4, 128, 1), blk, 0, stream>>>(
        query, nullptr, nullptr, WqhT, WqlT, nullptr, qh, ql, nullptr,
        DD, DD, 0, 0, 0, 1.0f);
    mm_nt<0><<<dim3(4, 128, 1), blk, 0, stream>>>(
        key, nullptr, nullptr, WkhT, WklT, nullptr, kh, kl, nullptr,
        DD, DD, 0, 0, 0, 1.0f);
    // v projection, 1-product, writes vT fp16
    mm_nt<1><<<dim3(4, 128, 1), blk, 0, stream>>>(
        value, nullptr, nullptr, WvhT, nullptr, nullptr, vT, nullptr, nullptr,
        DD, DD, 0, 0, 0, 1.0f);

    // scores = q k^T / sqrt(d) + diag(min(exp(si),3)), 3-product
    mm_nt<2><<<dim3(16, 16, BB), blk, 0, stream>>>(
        nullptr, qh, ql, kh, kl, attn, nullptr, nullptr, si,
        NN, DD, (long)NN * DD, (long)NN * DD, (long)NN * NN, inv_sqrt_d);

    // softmax in-place + entropy partials + fp16 attn copy
    softmax_entropy_kernel<<<dim3(BB * NN), blk, 0, stream>>>(attn, attn_h, partials);
    ent_reduce_kernel<<<dim3(1), blk, 0, stream>>>(partials, ent);

    // out = attn @ v : A = attn fp16 [2048][2048], B = vT fp16 [512][2048]
    mm_nt<3><<<dim3(4, 16, BB), blk, 0, stream>>>(
        nullptr, attn_h, nullptr, vT, nullptr, out, nullptr, nullptr, nullptr,
        DD, NN, (long)NN * NN, (long)DD * NN, (long)NN * DD, 1.0f);
}